// Round 1
// baseline (6989.972 us; speedup 1.0000x reference)
//
#include <hip/hip_runtime.h>
#include <math.h>

// Problem constants (fixed by setup_inputs)
#define M     4096      // source rows
#define NTGT  65536     // target rows
#define KD    1024      // feature dim
#define TOPK  4

// Fused GEMM+topk tiling
#define NS    32            // target slices (grid.y)
#define SLICE (NTGT / NS)   // 2048 targets per workgroup
#define BM    128
#define BN    128
#define BK    16
#define NTILE (SLICE / BN)  // 16
#define LDA   132           // padded LDS row stride (floats)
#define LDSS  33            // scan-stage row stride

// ---------------------------------------------------------------------------
// Kernel A: per-target inverse norms. 4 waves/block, 1 wave per target row.
// ---------------------------------------------------------------------------
__global__ void tinv_kernel(const float* __restrict__ T, float* __restrict__ tinv) {
    const int wave = threadIdx.x >> 6;
    const int lane = threadIdx.x & 63;
    const int row  = blockIdx.x * 4 + wave;
    const float* p = T + (size_t)row * KD;
    float s = 0.f;
#pragma unroll
    for (int j = 0; j < 4; ++j) {
        float4 v = *reinterpret_cast<const float4*>(p + lane * 4 + j * 256);
        s += v.x * v.x + v.y * v.y + v.z * v.z + v.w * v.w;
    }
#pragma unroll
    for (int off = 32; off; off >>= 1) s += __shfl_xor(s, off);
    if (lane == 0) tinv[row] = 1.0f / sqrtf(fmaxf(s, 1e-24f));
}

// ---------------------------------------------------------------------------
// Kernel B: fused fp32 GEMM + running top-4 per source row over one N-slice.
// Workgroup: 256 threads (16x16), 8x8 register tile -> 128x128 sim tile.
// Row-owner threads (tid<128) keep the running top-4 in registers.
// ---------------------------------------------------------------------------
__global__ __launch_bounds__(256, 2)
void simtopk_kernel(const float* __restrict__ S, const float* __restrict__ T,
                    const float* __restrict__ tinv,
                    float* __restrict__ pval, int* __restrict__ pidx) {
    __shared__ float smem[2 * BK * LDA];   // As | Bs ; overlaid by Ss (scan stage)
    __shared__ float tinvS[BN];
    float* As = smem;
    float* Bs = smem + BK * LDA;
    float* Ss = smem;                      // 128*33 = 4224 <= 2*16*132 = 4224

    const int tid = threadIdx.x;
    const int tx = tid & 15, ty = tid >> 4;
    const int rb   = blockIdx.x;
    const int tgt0 = blockIdx.y * SLICE;
    const size_t abase = (size_t)(rb * BM) * KD;

    float t0 = -INFINITY, t1 = -INFINITY, t2 = -INFINITY, t3 = -INFINITY;
    int   i0 = 0, i1 = 0, i2 = 0, i3 = 0;

    for (int nt = 0; nt < NTILE; ++nt) {
        const int tb = tgt0 + nt * BN;

        float acc[8][8];
#pragma unroll
        for (int i = 0; i < 8; ++i)
#pragma unroll
            for (int j = 0; j < 8; ++j) acc[i][j] = 0.f;

        for (int kk = 0; kk < KD; kk += BK) {
            // stage A (128x16) and B (128x16) tiles, transposed into [BK][BM+pad]
            {
                const int r  = tid >> 2;          // 0..63
                const int c4 = (tid & 3) * 4;     // 0,4,8,12
#pragma unroll
                for (int h = 0; h < 2; ++h) {
                    const int row = r + h * 64;
                    float4 av = *reinterpret_cast<const float4*>(S + abase + (size_t)row * KD + kk + c4);
                    float4 bv = *reinterpret_cast<const float4*>(T + (size_t)(tb + row) * KD + kk + c4);
                    As[(c4 + 0) * LDA + row] = av.x;
                    As[(c4 + 1) * LDA + row] = av.y;
                    As[(c4 + 2) * LDA + row] = av.z;
                    As[(c4 + 3) * LDA + row] = av.w;
                    Bs[(c4 + 0) * LDA + row] = bv.x;
                    Bs[(c4 + 1) * LDA + row] = bv.y;
                    Bs[(c4 + 2) * LDA + row] = bv.z;
                    Bs[(c4 + 3) * LDA + row] = bv.w;
                }
            }
            __syncthreads();
#pragma unroll
            for (int k = 0; k < BK; ++k) {
                float a[8], b[8];
                *reinterpret_cast<float4*>(&a[0]) = *reinterpret_cast<float4*>(&As[k * LDA + ty * 8]);
                *reinterpret_cast<float4*>(&a[4]) = *reinterpret_cast<float4*>(&As[k * LDA + ty * 8 + 4]);
                *reinterpret_cast<float4*>(&b[0]) = *reinterpret_cast<float4*>(&Bs[k * LDA + tx * 4]);
                *reinterpret_cast<float4*>(&b[4]) = *reinterpret_cast<float4*>(&Bs[k * LDA + 64 + tx * 4]);
#pragma unroll
                for (int i = 0; i < 8; ++i)
#pragma unroll
                    for (int j = 0; j < 8; ++j)
                        acc[i][j] = fmaf(a[i], b[j], acc[i][j]);
            }
            __syncthreads();
        }

        // per-target inverse norms for this tile
        if (tid < BN) tinvS[tid] = tinv[tb + tid];
        __syncthreads();

        // scan 128 cols in 4 chunks of 32; row-owner threads update top-4 regs.
        // acc[i][j]: row = ty*8+i ; col = (j<4) ? 4*tx+j : 64 + 4*tx + (j-4)
#pragma unroll
        for (int cc = 0; cc < 4; ++cc) {
            const int g = cc >> 1;                 // which 64-col group
            if ((tx >> 3) == (cc & 1)) {
                const int txl = tx & 7;
#pragma unroll
                for (int i = 0; i < 8; ++i) {
                    const int rrow = ty * 8 + i;
#pragma unroll
                    for (int j = 0; j < 4; ++j) {
                        const int colc = 4 * txl + j;   // col within chunk
                        Ss[rrow * LDSS + colc] = acc[i][g * 4 + j] * tinvS[cc * 32 + colc];
                    }
                }
            }
            __syncthreads();
            if (tid < BM) {
#pragma unroll 4
                for (int c = 0; c < 32; ++c) {
                    const float v = Ss[tid * LDSS + c];
                    if (v > t3) {
                        const int gi = tb + cc * 32 + c;
                        if (v > t0)      { t3=t2;i3=i2; t2=t1;i2=i1; t1=t0;i1=i0; t0=v;i0=gi; }
                        else if (v > t1) { t3=t2;i3=i2; t2=t1;i2=i1; t1=v;i1=gi; }
                        else if (v > t2) { t3=t2;i3=i2; t2=v;i2=gi; }
                        else             { t3=v;i3=gi; }
                    }
                }
            }
            __syncthreads();
        }
    }

    if (tid < BM) {
        const int row = rb * BM + tid;
        const size_t base = ((size_t)blockIdx.y * M + row) * 4;
        pval[base + 0] = t0; pval[base + 1] = t1; pval[base + 2] = t2; pval[base + 3] = t3;
        pidx[base + 0] = i0; pidx[base + 1] = i1; pidx[base + 2] = i2; pidx[base + 3] = i3;
    }
}

// ---------------------------------------------------------------------------
// Kernel C: merge NS partial top-4s -> global top-4, gather + mean.
// One block (256 threads) per source row.
// ---------------------------------------------------------------------------
__global__ void merge_kernel(const float* __restrict__ pval, const int* __restrict__ pidx,
                             const float* __restrict__ T, float* __restrict__ out) {
    __shared__ float cv[NS * 4];
    __shared__ int   ci[NS * 4];
    __shared__ int   sel[4];
    const int r = blockIdx.x;
    const int tid = threadIdx.x;

    if (tid < NS * 4) {
        const int s = tid >> 2, q = tid & 3;
        const size_t base = ((size_t)s * M + r) * 4 + q;
        cv[tid] = pval[base];
        ci[tid] = pidx[base];
    }
    __syncthreads();

    if (tid == 0) {
        float t0 = -INFINITY, t1 = -INFINITY, t2 = -INFINITY, t3 = -INFINITY;
        int   j0 = 0, j1 = 0, j2 = 0, j3 = 0;
        for (int c = 0; c < NS * 4; ++c) {
            const float v = cv[c];
            if (v > t3) {
                const int gi = ci[c];
                if (v > t0)      { t3=t2;j3=j2; t2=t1;j2=j1; t1=t0;j1=j0; t0=v;j0=gi; }
                else if (v > t1) { t3=t2;j3=j2; t2=t1;j2=j1; t1=v;j1=gi; }
                else if (v > t2) { t3=t2;j3=j2; t2=v;j2=gi; }
                else             { t3=v;j3=gi; }
            }
        }
        sel[0] = j0; sel[1] = j1; sel[2] = j2; sel[3] = j3;
    }
    __syncthreads();

    const int d = tid * 4;
    float4 a = make_float4(0.f, 0.f, 0.f, 0.f);
#pragma unroll
    for (int q = 0; q < 4; ++q) {
        const float4 v = *reinterpret_cast<const float4*>(T + (size_t)sel[q] * KD + d);
        a.x += v.x; a.y += v.y; a.z += v.z; a.w += v.w;
    }
    a.x *= 0.25f; a.y *= 0.25f; a.z *= 0.25f; a.w *= 0.25f;
    *reinterpret_cast<float4*>(out + (size_t)r * KD + d) = a;
}

// ---------------------------------------------------------------------------
extern "C" void kernel_launch(void* const* d_in, const int* in_sizes, int n_in,
                              void* d_out, int out_size, void* d_ws, size_t ws_size,
                              hipStream_t stream) {
    const float* S = (const float*)d_in[0];   // [4096,1024]
    const float* T = (const float*)d_in[1];   // [65536,1024]
    float* out = (float*)d_out;               // [4096,1024]

    float* tinv = (float*)d_ws;                          // 65536 floats
    float* pval = tinv + NTGT;                           // NS*M*4 floats (2 MB)
    int*   pidx = (int*)(pval + (size_t)NS * M * 4);     // NS*M*4 ints  (2 MB)

    tinv_kernel<<<NTGT / 4, 256, 0, stream>>>(T, tinv);
    simtopk_kernel<<<dim3(M / BM, NS), 256, 0, stream>>>(S, T, tinv, pval, pidx);
    merge_kernel<<<M, 256, 0, stream>>>(pval, pidx, T, out);
}

// Round 2
// 1130.934 us; speedup vs baseline: 6.1807x; 6.1807x over previous
//
#include <hip/hip_runtime.h>
#include <math.h>
#include <stdint.h>

// Problem constants (fixed by setup_inputs)
#define M     4096      // source rows
#define NTGT  65536     // target rows
#define KD    1024      // feature dim

// Screen-kernel tiling
#define NS    32            // target slices (grid.y)
#define SLICE (NTGT / NS)   // 2048 targets per block
#define BT    128           // targets per tile (MFMA M)
#define BS    128           // sources per block (MFMA N)
#define BK    32            // K step (one 16x16x32 MFMA)
#define NTILE (SLICE / BT)  // 16

typedef __attribute__((ext_vector_type(8))) short bf16x8;   // 4 VGPRs of bf16
typedef __attribute__((ext_vector_type(4))) float f32x4;

// ---------------------------------------------------------------------------
// helpers
// ---------------------------------------------------------------------------
__device__ __forceinline__ ushort f2bf(float f) {
    uint32_t u = __float_as_uint(f);
    uint32_t r = (u + 0x7FFFu + ((u >> 16) & 1u)) >> 16;   // RNE; no NaN inputs
    return (ushort)r;
}

template <int NK>
__device__ __forceinline__ void insert_desc(uint32_t (&arr)[NK], uint32_t pk) {
    uint32_t cur = pk;
#pragma unroll
    for (int s = 0; s < NK; ++s) {
        uint32_t old = arr[s];
        bool g = __uint_as_float(cur) > __uint_as_float(old);
        arr[s] = g ? cur : old;
        cur    = g ? old : cur;
    }
}

__device__ __forceinline__ void gload16(const void* g, void* l) {
    __builtin_amdgcn_global_load_lds(
        (const __attribute__((address_space(1))) unsigned int*)g,
        (__attribute__((address_space(3))) unsigned int*)l, 16, 0, 0);
}

// ---------------------------------------------------------------------------
// Prep A: per-target inverse norm + normalized bf16 target copy
// 4 waves/block, one wave per row.
// ---------------------------------------------------------------------------
__global__ void prep_targets(const float* __restrict__ T, float* __restrict__ tinv,
                             ushort* __restrict__ Tb) {
    const int wave = threadIdx.x >> 6;
    const int lane = threadIdx.x & 63;
    const int row  = blockIdx.x * 4 + wave;
    const float* p = T + (size_t)row * KD;
    float4 v[4];
    float s = 0.f;
#pragma unroll
    for (int j = 0; j < 4; ++j) {
        v[j] = *reinterpret_cast<const float4*>(p + lane * 4 + j * 256);
        s += v[j].x * v[j].x + v[j].y * v[j].y + v[j].z * v[j].z + v[j].w * v[j].w;
    }
#pragma unroll
    for (int off = 32; off; off >>= 1) s += __shfl_xor(s, off);
    const float rinv = 1.0f / sqrtf(fmaxf(s, 1e-24f));
    if (lane == 0) tinv[row] = rinv;
#pragma unroll
    for (int j = 0; j < 4; ++j) {
        ushort4 o;
        o.x = f2bf(v[j].x * rinv); o.y = f2bf(v[j].y * rinv);
        o.z = f2bf(v[j].z * rinv); o.w = f2bf(v[j].w * rinv);
        *reinterpret_cast<ushort4*>(Tb + (size_t)row * KD + lane * 4 + j * 256) = o;
    }
}

// Prep B: raw bf16 source copy (source norm does not affect per-row ranking)
__global__ void prep_source(const float* __restrict__ S, ushort* __restrict__ Sb) {
    const int wave = threadIdx.x >> 6;
    const int lane = threadIdx.x & 63;
    const int row  = blockIdx.x * 4 + wave;
    const float* p = S + (size_t)row * KD;
#pragma unroll
    for (int j = 0; j < 4; ++j) {
        float4 v = *reinterpret_cast<const float4*>(p + lane * 4 + j * 256);
        ushort4 o;
        o.x = f2bf(v.x); o.y = f2bf(v.y); o.z = f2bf(v.z); o.w = f2bf(v.w);
        *reinterpret_cast<ushort4*>(Sb + (size_t)row * KD + lane * 4 + j * 256) = o;
    }
}

// ---------------------------------------------------------------------------
// Screen: bf16 MFMA GEMM (targets x sources) + per-lane packed top-8 per
// source column; slice-level top-8 merged in LDS at block end.
// 256 threads = 4 waves arranged 2 (target halves) x 2 (source halves).
// ---------------------------------------------------------------------------
__global__ __launch_bounds__(256, 2)
void screen_kernel(const ushort* __restrict__ Sb, const ushort* __restrict__ Tb,
                   uint32_t* __restrict__ cand_out) {
    __shared__ __align__(16) unsigned char lds_raw[33280];  // A(8K)|B(8K); mbuf 128x65 u32

    const int tid  = threadIdx.x;
    const int lane = tid & 63, wid = tid >> 6;
    const int wr = wid >> 1, wc = wid & 1;
    const int l15 = lane & 15, l4 = lane >> 4;
    const int sb   = blockIdx.x * BS;
    const int tgt0 = blockIdx.y * SLICE;

    // staging: thread stages 16B; rows r and r+64 of each 128x32 tile
    const int srow = tid >> 2;          // 0..63
    const int scol = (tid & 3) * 8;     // bf16 element offset
    const ushort* bSrc = Sb + (size_t)(sb + srow) * KD + scol;
    void* ldsA0 = lds_raw + wid * 1024;
    void* ldsA1 = lds_raw + 4096 + wid * 1024;
    void* ldsB0 = lds_raw + 8192 + wid * 1024;
    void* ldsB1 = lds_raw + 8192 + 4096 + wid * 1024;

    // fragment LDS byte offsets (constant across K-iters)
    int aOff[4], bOff[4];
#pragma unroll
    for (int m = 0; m < 4; ++m) aOff[m] = (wr * 64 + m * 16 + l15) * 64 + l4 * 16;
#pragma unroll
    for (int n = 0; n < 4; ++n) bOff[n] = 8192 + (wc * 64 + n * 16 + l15) * 64 + l4 * 16;

    uint32_t cand[4][8];
#pragma unroll
    for (int n = 0; n < 4; ++n)
#pragma unroll
        for (int j = 0; j < 8; ++j) cand[n][j] = 0xFF800000u;   // -inf, idx 0

    for (int nt = 0; nt < NTILE; ++nt) {
        const int tb = tgt0 + nt * BT;
        const ushort* aSrc = Tb + (size_t)(tb + srow) * KD + scol;

        f32x4 acc[4][4];
#pragma unroll
        for (int m = 0; m < 4; ++m)
#pragma unroll
            for (int n = 0; n < 4; ++n) acc[m][n] = (f32x4){0.f, 0.f, 0.f, 0.f};

        for (int kk = 0; kk < KD; kk += BK) {
            gload16(aSrc + kk,           ldsA0);
            gload16(aSrc + 64 * KD + kk, ldsA1);
            gload16(bSrc + kk,           ldsB0);
            gload16(bSrc + 64 * KD + kk, ldsB1);
            asm volatile("s_waitcnt vmcnt(0)" ::: "memory");
            __syncthreads();

            bf16x8 af[4], bfv[4];
#pragma unroll
            for (int m = 0; m < 4; ++m)
                af[m] = *reinterpret_cast<const bf16x8*>(lds_raw + aOff[m]);
#pragma unroll
            for (int n = 0; n < 4; ++n)
                bfv[n] = *reinterpret_cast<const bf16x8*>(lds_raw + bOff[n]);
#pragma unroll
            for (int m = 0; m < 4; ++m)
#pragma unroll
                for (int n = 0; n < 4; ++n)
                    acc[m][n] = __builtin_amdgcn_mfma_f32_16x16x32_bf16(af[m], bfv[n], acc[m][n], 0, 0, 0);
            __syncthreads();
        }

        // screen: C layout col=l15 (source), row=(l4*4+q) within fragment (target)
#pragma unroll
        for (int n = 0; n < 4; ++n) {
            float c7 = __uint_as_float(cand[n][7]);
#pragma unroll
            for (int m = 0; m < 4; ++m) {
#pragma unroll
                for (int q = 0; q < 4; ++q) {
                    const float v = acc[m][n][q];
                    if (v > c7) {
                        const int tg = tb + wr * 64 + m * 16 + l4 * 4 + q;
                        const uint32_t pk = (__float_as_uint(v) & 0xFFFF0000u) | (uint32_t)tg;
                        insert_desc<8>(cand[n], pk);
                        c7 = __uint_as_float(cand[n][7]);
                    }
                }
            }
        }
    }

    // slice merge: 8 owner-lanes x 8 cands per source -> top-8 per (slice, source)
    __syncthreads();
    uint32_t* mbuf = (uint32_t*)lds_raw;     // [128][65]
#pragma unroll
    for (int n = 0; n < 4; ++n) {
        const int sc   = wc * 64 + n * 16 + l15;
        const int slot = wr * 32 + l4 * 8;
#pragma unroll
        for (int j = 0; j < 8; ++j) mbuf[sc * 65 + slot + j] = cand[n][j];
    }
    __syncthreads();
    if (tid < BS) {
        uint32_t best[8];
#pragma unroll
        for (int j = 0; j < 8; ++j) best[j] = 0xFF800000u;
        const uint32_t* rowp = mbuf + tid * 65;
        for (int c = 0; c < 64; ++c) {
            const uint32_t pk = rowp[c];
            if (__uint_as_float(pk) > __uint_as_float(best[7])) insert_desc<8>(best, pk);
        }
        uint32_t* dst = cand_out + (size_t)(sb + tid) * 256 + blockIdx.y * 8;
#pragma unroll
        for (int j = 0; j < 8; ++j) dst[j] = best[j];
    }
}

// ---------------------------------------------------------------------------
// Final: per source row, screen-top-16 of 256 candidates -> fp32 rescore ->
// exact top-4 -> gather + mean. One block (256 threads) per row.
// ---------------------------------------------------------------------------
__global__ __launch_bounds__(256)
void final_kernel(const uint32_t* __restrict__ cand_out, const float* __restrict__ S,
                  const float* __restrict__ T, const float* __restrict__ tinv,
                  float* __restrict__ out) {
    __shared__ uint32_t cl[256];
    __shared__ __align__(16) float srow[KD];
    __shared__ float rv[16];
    __shared__ int   ri[16];
    __shared__ int   sel[4];

    const int r = blockIdx.x;
    const int tid = threadIdx.x;

    cl[tid] = cand_out[(size_t)r * 256 + tid];
    *reinterpret_cast<float4*>(srow + tid * 4) =
        *reinterpret_cast<const float4*>(S + (size_t)r * KD + tid * 4);
    __syncthreads();

    if (tid == 0) {
        uint32_t best[16];
#pragma unroll
        for (int j = 0; j < 16; ++j) best[j] = 0xFF800000u;
        for (int c = 0; c < 256; ++c) {
            const uint32_t pk = cl[c];
            if (__uint_as_float(pk) > __uint_as_float(best[15])) insert_desc<16>(best, pk);
        }
#pragma unroll
        for (int j = 0; j < 16; ++j) ri[j] = (int)(best[j] & 0xFFFFu);
    }
    __syncthreads();

    const int lane = tid & 63, wv = tid >> 6;
    for (int c = wv; c < 16; c += 4) {
        const int idx = ri[c];
        const float* tp = T + (size_t)idx * KD;
        float s = 0.f;
#pragma unroll
        for (int j = 0; j < 4; ++j) {
            const float4 tv = *reinterpret_cast<const float4*>(tp + lane * 4 + j * 256);
            const float4 sv = *reinterpret_cast<const float4*>(srow + lane * 4 + j * 256);
            s += tv.x * sv.x + tv.y * sv.y + tv.z * sv.z + tv.w * sv.w;
        }
#pragma unroll
        for (int off = 32; off; off >>= 1) s += __shfl_xor(s, off);
        if (lane == 0) rv[c] = s * tinv[idx];
    }
    __syncthreads();

    if (tid == 0) {
        float b0 = -INFINITY, b1 = -INFINITY, b2 = -INFINITY, b3 = -INFINITY;
        int s0 = 0, s1 = 0, s2 = 0, s3 = 0;
        for (int c = 0; c < 16; ++c) {
            const float v = rv[c]; const int id = ri[c];
            if (v > b3) {
                if (v > b0)      { b3=b2;s3=s2; b2=b1;s2=s1; b1=b0;s1=s0; b0=v;s0=id; }
                else if (v > b1) { b3=b2;s3=s2; b2=b1;s2=s1; b1=v;s1=id; }
                else if (v > b2) { b3=b2;s3=s2; b2=v;s2=id; }
                else             { b3=v;s3=id; }
            }
        }
        sel[0]=s0; sel[1]=s1; sel[2]=s2; sel[3]=s3;
    }
    __syncthreads();

    float4 a = make_float4(0.f, 0.f, 0.f, 0.f);
#pragma unroll
    for (int q = 0; q < 4; ++q) {
        const float4 v = *reinterpret_cast<const float4*>(T + (size_t)sel[q] * KD + tid * 4);
        a.x += v.x; a.y += v.y; a.z += v.z; a.w += v.w;
    }
    a.x *= 0.25f; a.y *= 0.25f; a.z *= 0.25f; a.w *= 0.25f;
    *reinterpret_cast<float4*>(out + (size_t)r * KD + tid * 4) = a;
}

// ===========================================================================
// Fallback (round-1 proven fp32 path) — used only if ws_size is too small.
// ===========================================================================
#define FNS    32
#define FSLICE (NTGT / FNS)
#define FBM 128
#define FBN 128
#define FBK 16
#define FNTILE (FSLICE / FBN)
#define FLDA 132
#define FLDSS 33

__global__ void tinv_kernel(const float* __restrict__ T, float* __restrict__ tinv) {
    const int wave = threadIdx.x >> 6;
    const int lane = threadIdx.x & 63;
    const int row  = blockIdx.x * 4 + wave;
    const float* p = T + (size_t)row * KD;
    float s = 0.f;
#pragma unroll
    for (int j = 0; j < 4; ++j) {
        float4 v = *reinterpret_cast<const float4*>(p + lane * 4 + j * 256);
        s += v.x * v.x + v.y * v.y + v.z * v.z + v.w * v.w;
    }
#pragma unroll
    for (int off = 32; off; off >>= 1) s += __shfl_xor(s, off);
    if (lane == 0) tinv[row] = 1.0f / sqrtf(fmaxf(s, 1e-24f));
}

__global__ __launch_bounds__(256, 2)
void simtopk_kernel(const float* __restrict__ S, const float* __restrict__ T,
                    const float* __restrict__ tinv,
                    float* __restrict__ pval, int* __restrict__ pidx) {
    __shared__ float smem[2 * FBK * FLDA];
    __shared__ float tinvS[FBN];
    float* As = smem;
    float* Bs = smem + FBK * FLDA;
    float* Ss = smem;

    const int tid = threadIdx.x;
    const int tx = tid & 15, ty = tid >> 4;
    const int rb   = blockIdx.x;
    const int tgt0 = blockIdx.y * FSLICE;
    const size_t abase = (size_t)(rb * FBM) * KD;

    float t0 = -INFINITY, t1 = -INFINITY, t2 = -INFINITY, t3 = -INFINITY;
    int   i0 = 0, i1 = 0, i2 = 0, i3 = 0;

    for (int nt = 0; nt < FNTILE; ++nt) {
        const int tb = tgt0 + nt * FBN;
        float acc[8][8];
#pragma unroll
        for (int i = 0; i < 8; ++i)
#pragma unroll
            for (int j = 0; j < 8; ++j) acc[i][j] = 0.f;

        for (int kk = 0; kk < KD; kk += FBK) {
            const int rr = tid >> 2;
            const int c4 = (tid & 3) * 4;
#pragma unroll
            for (int h = 0; h < 2; ++h) {
                const int row = rr + h * 64;
                float4 av = *reinterpret_cast<const float4*>(S + abase + (size_t)row * KD + kk + c4);
                float4 bv = *reinterpret_cast<const float4*>(T + (size_t)(tb + row) * KD + kk + c4);
                As[(c4 + 0) * FLDA + row] = av.x; As[(c4 + 1) * FLDA + row] = av.y;
                As[(c4 + 2) * FLDA + row] = av.z; As[(c4 + 3) * FLDA + row] = av.w;
                Bs[(c4 + 0) * FLDA + row] = bv.x; Bs[(c4 + 1) * FLDA + row] = bv.y;
                Bs[(c4 + 2) * FLDA + row] = bv.z; Bs[(c4 + 3) * FLDA + row] = bv.w;
            }
            __syncthreads();
#pragma unroll
            for (int k = 0; k < FBK; ++k) {
                float a[8], b[8];
                *reinterpret_cast<float4*>(&a[0]) = *reinterpret_cast<float4*>(&As[k * FLDA + ty * 8]);
                *reinterpret_cast<float4*>(&a[4]) = *reinterpret_cast<float4*>(&As[k * FLDA + ty * 8 + 4]);
                *reinterpret_cast<float4*>(&b[0]) = *reinterpret_cast<float4*>(&Bs[k * FLDA + tx * 4]);
                *reinterpret_cast<float4*>(&b[4]) = *reinterpret_cast<float4*>(&Bs[k * FLDA + 64 + tx * 4]);
#pragma unroll
                for (int i = 0; i < 8; ++i)
#pragma unroll
                    for (int j = 0; j < 8; ++j)
                        acc[i][j] = fmaf(a[i], b[j], acc[i][j]);
            }
            __syncthreads();
        }

        if (tid < FBN) tinvS[tid] = tinv[tb + tid];
        __syncthreads();

#pragma unroll
        for (int cc = 0; cc < 4; ++cc) {
            const int g = cc >> 1;
            if ((tx >> 3) == (cc & 1)) {
                const int txl = tx & 7;
#pragma unroll
                for (int i = 0; i < 8; ++i) {
                    const int rrow = ty * 8 + i;
#pragma unroll
                    for (int j = 0; j < 4; ++j) {
                        const int colc = 4 * txl + j;
                        Ss[rrow * FLDSS + colc] = acc[i][g * 4 + j] * tinvS[cc * 32 + colc];
                    }
                }
            }
            __syncthreads();
            if (tid < FBM) {
#pragma unroll 4
                for (int c = 0; c < 32; ++c) {
                    const float v = Ss[tid * FLDSS + c];
                    if (v > t3) {
                        const int gi = tb + cc * 32 + c;
                        if (v > t0)      { t3=t2;i3=i2; t2=t1;i2=i1; t1=t0;i1=i0; t0=v;i0=gi; }
                        else if (v > t1) { t3=t2;i3=i2; t2=t1;i2=i1; t1=v;i1=gi; }
                        else if (v > t2) { t3=t2;i3=i2; t2=v;i2=gi; }
                        else             { t3=v;i3=gi; }
                    }
                }
            }
            __syncthreads();
        }
    }

    if (tid < FBM) {
        const int row = rb * FBM + tid;
        const size_t base = ((size_t)blockIdx.y * M + row) * 4;
        pval[base + 0] = t0; pval[base + 1] = t1; pval[base + 2] = t2; pval[base + 3] = t3;
        pidx[base + 0] = i0; pidx[base + 1] = i1; pidx[base + 2] = i2; pidx[base + 3] = i3;
    }
}

__global__ void merge_kernel(const float* __restrict__ pval, const int* __restrict__ pidx,
                             const float* __restrict__ T, float* __restrict__ out) {
    __shared__ float cv[FNS * 4];
    __shared__ int   ci[FNS * 4];
    __shared__ int   sel[4];
    const int r = blockIdx.x;
    const int tid = threadIdx.x;

    if (tid < FNS * 4) {
        const int s = tid >> 2, q = tid & 3;
        const size_t base = ((size_t)s * M + r) * 4 + q;
        cv[tid] = pval[base];
        ci[tid] = pidx[base];
    }
    __syncthreads();

    if (tid == 0) {
        float t0 = -INFINITY, t1 = -INFINITY, t2 = -INFINITY, t3 = -INFINITY;
        int   j0 = 0, j1 = 0, j2 = 0, j3 = 0;
        for (int c = 0; c < FNS * 4; ++c) {
            const float v = cv[c];
            if (v > t3) {
                const int gi = ci[c];
                if (v > t0)      { t3=t2;j3=j2; t2=t1;j2=j1; t1=t0;j1=j0; t0=v;j0=gi; }
                else if (v > t1) { t3=t2;j3=j2; t2=t1;j2=j1; t1=v;j1=gi; }
                else if (v > t2) { t3=t2;j3=j2; t2=v;j2=gi; }
                else             { t3=v;j3=gi; }
            }
        }
        sel[0] = j0; sel[1] = j1; sel[2] = j2; sel[3] = j3;
    }
    __syncthreads();

    const int d = tid * 4;
    float4 a = make_float4(0.f, 0.f, 0.f, 0.f);
#pragma unroll
    for (int q = 0; q < 4; ++q) {
        const float4 v = *reinterpret_cast<const float4*>(T + (size_t)sel[q] * KD + d);
        a.x += v.x; a.y += v.y; a.z += v.z; a.w += v.w;
    }
    a.x *= 0.25f; a.y *= 0.25f; a.z *= 0.25f; a.w *= 0.25f;
    *reinterpret_cast<float4*>(out + (size_t)r * KD + d) = a;
}

// ---------------------------------------------------------------------------
extern "C" void kernel_launch(void* const* d_in, const int* in_sizes, int n_in,
                              void* d_out, int out_size, void* d_ws, size_t ws_size,
                              hipStream_t stream) {
    const float* S = (const float*)d_in[0];   // [4096,1024]
    const float* T = (const float*)d_in[1];   // [65536,1024]
    float* out = (float*)d_out;               // [4096,1024]

    const size_t sz_tinv = (size_t)NTGT * 4;                 // 256 KB
    const size_t sz_Sb   = (size_t)M * KD * 2;               // 8 MB
    const size_t sz_Tb   = (size_t)NTGT * KD * 2;            // 128 MB
    const size_t sz_cand = (size_t)M * 256 * 4;              // 4 MB
    const size_t need = sz_tinv + sz_Sb + sz_Tb + sz_cand;   // ~140.3 MB

    if (ws_size >= need) {
        float*    tinv = (float*)d_ws;
        ushort*   Sb   = (ushort*)((char*)d_ws + sz_tinv);
        ushort*   Tb   = (ushort*)((char*)d_ws + sz_tinv + sz_Sb);
        uint32_t* cand = (uint32_t*)((char*)d_ws + sz_tinv + sz_Sb + sz_Tb);

        prep_targets<<<NTGT / 4, 256, 0, stream>>>(T, tinv, Tb);
        prep_source<<<M / 4, 256, 0, stream>>>(S, Sb);
        screen_kernel<<<dim3(M / BS, NS), 256, 0, stream>>>(Sb, Tb, cand);
        final_kernel<<<M, 256, 0, stream>>>(cand, S, T, tinv, out);
    } else {
        // round-1 fp32 fallback (~7 ms, proven correct)
        float* tinv = (float*)d_ws;
        float* pval = tinv + NTGT;
        int*   pidx = (int*)(pval + (size_t)FNS * M * 4);

        tinv_kernel<<<NTGT / 4, 256, 0, stream>>>(T, tinv);
        simtopk_kernel<<<dim3(M / FBM, FNS), 256, 0, stream>>>(S, T, tinv, pval, pidx);
        merge_kernel<<<M, 256, 0, stream>>>(pval, pidx, T, out);
    }
}

// Round 3
// 1036.680 us; speedup vs baseline: 6.7427x; 1.0909x over previous
//
#include <hip/hip_runtime.h>
#include <math.h>
#include <stdint.h>

// Problem constants (fixed by setup_inputs)
#define M     4096      // source rows
#define NTGT  65536     // target rows
#define KD    1024      // feature dim

// Screen-kernel tiling
#define NS    32            // target slices (grid.y)
#define SLICE (NTGT / NS)   // 2048 targets per block
#define BT    128           // targets per tile (MFMA M)
#define BS    128           // sources per block (MFMA N)
#define BK    32            // K step (one 16x16x32 MFMA)
#define NTILE (SLICE / BT)  // 16
#define NSTEP (KD / BK)     // 32 K-steps per tile
#define NIDXT (NTILE * NSTEP) // 512 total K-steps

typedef __attribute__((ext_vector_type(8))) short bf16x8;   // 4 VGPRs of bf16
typedef __attribute__((ext_vector_type(4))) float f32x4;

// ---------------------------------------------------------------------------
// helpers
// ---------------------------------------------------------------------------
__device__ __forceinline__ ushort f2bf(float f) {
    uint32_t u = __float_as_uint(f);
    uint32_t r = (u + 0x7FFFu + ((u >> 16) & 1u)) >> 16;   // RNE; no NaN inputs
    return (ushort)r;
}

template <int NK>
__device__ __forceinline__ void insert_desc(uint32_t (&arr)[NK], uint32_t pk) {
    uint32_t cur = pk;
#pragma unroll
    for (int s = 0; s < NK; ++s) {
        uint32_t old = arr[s];
        bool g = __uint_as_float(cur) > __uint_as_float(old);
        arr[s] = g ? cur : old;
        cur    = g ? old : cur;
    }
}

__device__ __forceinline__ void gload16(const void* g, void* l) {
    __builtin_amdgcn_global_load_lds(
        (const __attribute__((address_space(1))) unsigned int*)g,
        (__attribute__((address_space(3))) unsigned int*)l, 16, 0, 0);
}

// ---------------------------------------------------------------------------
// Prep A: per-target inverse norm + normalized bf16 target copy
// ---------------------------------------------------------------------------
__global__ void prep_targets(const float* __restrict__ T, float* __restrict__ tinv,
                             ushort* __restrict__ Tb) {
    const int wave = threadIdx.x >> 6;
    const int lane = threadIdx.x & 63;
    const int row  = blockIdx.x * 4 + wave;
    const float* p = T + (size_t)row * KD;
    float4 v[4];
    float s = 0.f;
#pragma unroll
    for (int j = 0; j < 4; ++j) {
        v[j] = *reinterpret_cast<const float4*>(p + lane * 4 + j * 256);
        s += v[j].x * v[j].x + v[j].y * v[j].y + v[j].z * v[j].z + v[j].w * v[j].w;
    }
#pragma unroll
    for (int off = 32; off; off >>= 1) s += __shfl_xor(s, off);
    const float rinv = 1.0f / sqrtf(fmaxf(s, 1e-24f));
    if (lane == 0) tinv[row] = rinv;
#pragma unroll
    for (int j = 0; j < 4; ++j) {
        ushort4 o;
        o.x = f2bf(v[j].x * rinv); o.y = f2bf(v[j].y * rinv);
        o.z = f2bf(v[j].z * rinv); o.w = f2bf(v[j].w * rinv);
        *reinterpret_cast<ushort4*>(Tb + (size_t)row * KD + lane * 4 + j * 256) = o;
    }
}

// Prep B: raw bf16 source copy (source norm does not affect per-row ranking)
__global__ void prep_source(const float* __restrict__ S, ushort* __restrict__ Sb) {
    const int wave = threadIdx.x >> 6;
    const int lane = threadIdx.x & 63;
    const int row  = blockIdx.x * 4 + wave;
    const float* p = S + (size_t)row * KD;
#pragma unroll
    for (int j = 0; j < 4; ++j) {
        float4 v = *reinterpret_cast<const float4*>(p + lane * 4 + j * 256);
        ushort4 o;
        o.x = f2bf(v.x); o.y = f2bf(v.y); o.z = f2bf(v.z); o.w = f2bf(v.w);
        *reinterpret_cast<ushort4*>(Sb + (size_t)row * KD + lane * 4 + j * 256) = o;
    }
}

// ---------------------------------------------------------------------------
// Screen: bf16 MFMA GEMM (targets x sources) + per-lane packed top-8 per
// source column. Double-buffered LDS (T3-minimum 2-phase): issue next K-step's
// global_load_lds BEFORE current ds_read+MFMA; one vmcnt(0)+barrier per step.
// Candidate merge: in-wave shfl tree (4 owner lanes -> 1), then 8KB LDS merge.
// ---------------------------------------------------------------------------
__global__ __launch_bounds__(256, 2)
void screen_kernel(const ushort* __restrict__ Sb, const ushort* __restrict__ Tb,
                   uint32_t* __restrict__ cand_out) {
    // buf[cur]: A (8KB, 128 rows x 64B) | B (8KB). 2 buffers = 32KB.
    // merge buffer (8KB) overlays buf0 after the K-loops.
    __shared__ __align__(16) unsigned char lds_raw[32768];

    const int tid  = threadIdx.x;
    const int lane = tid & 63, wid = tid >> 6;
    const int wr = wid >> 1, wc = wid & 1;
    const int l15 = lane & 15, l4 = lane >> 4;
    const int sb   = blockIdx.x * BS;
    const int tgt0 = blockIdx.y * SLICE;

    // staging geometry: thread stages 16B; covers rows {srow, srow+64}
    const int srow = tid >> 2;          // 0..63
    const int scol = (tid & 3) * 8;     // bf16 element offset within K-step
    const ushort* aBase = Tb + (size_t)(tgt0 + srow) * KD + scol;
    const ushort* bBase = Sb + (size_t)(sb   + srow) * KD + scol;

    // fragment LDS byte offsets within a buffer (constant across K-iters)
    int aOff[4], bOff[4];
#pragma unroll
    for (int m = 0; m < 4; ++m) aOff[m] = (wr * 64 + m * 16 + l15) * 64 + l4 * 16;
#pragma unroll
    for (int n = 0; n < 4; ++n) bOff[n] = 8192 + (wc * 64 + n * 16 + l15) * 64 + l4 * 16;

    uint32_t cand[4][8];
#pragma unroll
    for (int n = 0; n < 4; ++n)
#pragma unroll
        for (int j = 0; j < 8; ++j) cand[n][j] = 0xFF800000u;   // -inf, idx 0

    // prologue: stage K-step 0 into buf 0
    {
        unsigned char* buf = lds_raw;
        gload16(aBase,            buf + wid * 1024);
        gload16(aBase + 64 * KD,  buf + 4096 + wid * 1024);
        gload16(bBase,            buf + 8192 + wid * 1024);
        gload16(bBase + 64 * KD,  buf + 8192 + 4096 + wid * 1024);
    }
    asm volatile("s_waitcnt vmcnt(0)" ::: "memory");
    __syncthreads();

    int cur = 0;
    for (int nt = 0; nt < NTILE; ++nt) {
        f32x4 acc[4][4];
#pragma unroll
        for (int m = 0; m < 4; ++m)
#pragma unroll
            for (int n = 0; n < 4; ++n) acc[m][n] = (f32x4){0.f, 0.f, 0.f, 0.f};

        for (int ks = 0; ks < NSTEP; ++ks) {
            const int idx = nt * NSTEP + ks;

            // prefetch next K-step into the other buffer (issue-early)
            if (idx + 1 < NIDXT) {
                const int nidx = idx + 1;
                const int aoff = (nidx >> 5) * (BT * KD) + ((nidx & 31) << 5);
                const int boff = (nidx & 31) << 5;
                unsigned char* nbuf = lds_raw + ((cur ^ 1) << 14);
                gload16(aBase + aoff,           nbuf + wid * 1024);
                gload16(aBase + aoff + 64 * KD, nbuf + 4096 + wid * 1024);
                gload16(bBase + boff,           nbuf + 8192 + wid * 1024);
                gload16(bBase + boff + 64 * KD, nbuf + 8192 + 4096 + wid * 1024);
            }

            // compute current K-step from buf[cur]
            const unsigned char* cbuf = lds_raw + (cur << 14);
            bf16x8 af[4], bfv[4];
#pragma unroll
            for (int m = 0; m < 4; ++m)
                af[m] = *reinterpret_cast<const bf16x8*>(cbuf + aOff[m]);
#pragma unroll
            for (int n = 0; n < 4; ++n)
                bfv[n] = *reinterpret_cast<const bf16x8*>(cbuf + bOff[n]);
#pragma unroll
            for (int m = 0; m < 4; ++m)
#pragma unroll
                for (int n = 0; n < 4; ++n)
                    acc[m][n] = __builtin_amdgcn_mfma_f32_16x16x32_bf16(af[m], bfv[n], acc[m][n], 0, 0, 0);

            asm volatile("s_waitcnt vmcnt(0)" ::: "memory");
            __syncthreads();
            cur ^= 1;
        }

        // screen: C layout col=l15 (source), row=(l4*4+q) within fragment (target)
        const int tb = tgt0 + nt * BT;
#pragma unroll
        for (int n = 0; n < 4; ++n) {
            float c7 = __uint_as_float(cand[n][7]);
#pragma unroll
            for (int m = 0; m < 4; ++m) {
#pragma unroll
                for (int q = 0; q < 4; ++q) {
                    const float v = acc[m][n][q];
                    if (v > c7) {
                        const int tg = tb + wr * 64 + m * 16 + l4 * 4 + q;
                        const uint32_t pk = (__float_as_uint(v) & 0xFFFF0000u) | (uint32_t)tg;
                        insert_desc<8>(cand[n], pk);
                        c7 = __uint_as_float(cand[n][7]);
                    }
                }
            }
        }
    }

    // ---- candidate merge ----
    // intra-wave: owner lanes of source column sc are {l15 + 16*l4}; tree-merge
    // l4={2,3} into {0,1}, then l4=1 into l4=0, via shfl_down of packed cands.
#pragma unroll
    for (int n = 0; n < 4; ++n) {
#pragma unroll
        for (int off = 32; off >= 16; off >>= 1) {
            uint32_t inc[8];
#pragma unroll
            for (int j = 0; j < 8; ++j)
                inc[j] = (uint32_t)__shfl_down((int)cand[n][j], off);
#pragma unroll
            for (int j = 0; j < 8; ++j)
                if (__uint_as_float(inc[j]) > __uint_as_float(cand[n][7]))
                    insert_desc<8>(cand[n], inc[j]);
        }
    }

    __syncthreads();           // all K-loop LDS reads complete (barrier above), reuse buf0
    uint32_t* mbuf = (uint32_t*)lds_raw;     // [128 sources][16 slots]
    if (l4 == 0) {
#pragma unroll
        for (int n = 0; n < 4; ++n) {
            const int sc = wc * 64 + n * 16 + l15;
#pragma unroll
            for (int j = 0; j < 8; ++j) mbuf[sc * 16 + wr * 8 + j] = cand[n][j];
        }
    }
    __syncthreads();

    if (tid < BS) {
        uint32_t best[8];
#pragma unroll
        for (int j = 0; j < 8; ++j) best[j] = 0xFF800000u;
        const uint32_t* rowp = mbuf + tid * 16;
#pragma unroll
        for (int c = 0; c < 16; ++c) {
            const uint32_t pk = rowp[c];
            if (__uint_as_float(pk) > __uint_as_float(best[7])) insert_desc<8>(best, pk);
        }
        uint32_t* dst = cand_out + (size_t)(sb + tid) * 256 + blockIdx.y * 8;
#pragma unroll
        for (int j = 0; j < 8; ++j) dst[j] = best[j];
    }
}

// ---------------------------------------------------------------------------
// Final: per source row, screen-top-16 of 256 candidates -> fp32 rescore ->
// exact top-4 -> gather + mean. One block (256 threads) per row.
// ---------------------------------------------------------------------------
__global__ __launch_bounds__(256)
void final_kernel(const uint32_t* __restrict__ cand_out, const float* __restrict__ S,
                  const float* __restrict__ T, const float* __restrict__ tinv,
                  float* __restrict__ out) {
    __shared__ uint32_t cl[256];
    __shared__ __align__(16) float srow[KD];
    __shared__ float rv[16];
    __shared__ int   ri[16];
    __shared__ int   sel[4];

    const int r = blockIdx.x;
    const int tid = threadIdx.x;

    cl[tid] = cand_out[(size_t)r * 256 + tid];
    *reinterpret_cast<float4*>(srow + tid * 4) =
        *reinterpret_cast<const float4*>(S + (size_t)r * KD + tid * 4);
    __syncthreads();

    if (tid == 0) {
        uint32_t best[16];
#pragma unroll
        for (int j = 0; j < 16; ++j) best[j] = 0xFF800000u;
        for (int c = 0; c < 256; ++c) {
            const uint32_t pk = cl[c];
            if (__uint_as_float(pk) > __uint_as_float(best[15])) insert_desc<16>(best, pk);
        }
#pragma unroll
        for (int j = 0; j < 16; ++j) ri[j] = (int)(best[j] & 0xFFFFu);
    }
    __syncthreads();

    const int lane = tid & 63, wv = tid >> 6;
    for (int c = wv; c < 16; c += 4) {
        const int idx = ri[c];
        const float* tp = T + (size_t)idx * KD;
        float s = 0.f;
#pragma unroll
        for (int j = 0; j < 4; ++j) {
            const float4 tv = *reinterpret_cast<const float4*>(tp + lane * 4 + j * 256);
            const float4 sv = *reinterpret_cast<const float4*>(srow + lane * 4 + j * 256);
            s += tv.x * sv.x + tv.y * sv.y + tv.z * sv.z + tv.w * sv.w;
        }
#pragma unroll
        for (int off = 32; off; off >>= 1) s += __shfl_xor(s, off);
        if (lane == 0) rv[c] = s * tinv[idx];
    }
    __syncthreads();

    if (tid == 0) {
        float b0 = -INFINITY, b1 = -INFINITY, b2 = -INFINITY, b3 = -INFINITY;
        int s0 = 0, s1 = 0, s2 = 0, s3 = 0;
        for (int c = 0; c < 16; ++c) {
            const float v = rv[c]; const int id = ri[c];
            if (v > b3) {
                if (v > b0)      { b3=b2;s3=s2; b2=b1;s2=s1; b1=b0;s1=s0; b0=v;s0=id; }
                else if (v > b1) { b3=b2;s3=s2; b2=b1;s2=s1; b1=v;s1=id; }
                else if (v > b2) { b3=b2;s3=s2; b2=v;s2=id; }
                else             { b3=v;s3=id; }
            }
        }
        sel[0]=s0; sel[1]=s1; sel[2]=s2; sel[3]=s3;
    }
    __syncthreads();

    float4 a = make_float4(0.f, 0.f, 0.f, 0.f);
#pragma unroll
    for (int q = 0; q < 4; ++q) {
        const float4 v = *reinterpret_cast<const float4*>(T + (size_t)sel[q] * KD + tid * 4);
        a.x += v.x; a.y += v.y; a.z += v.z; a.w += v.w;
    }
    a.x *= 0.25f; a.y *= 0.25f; a.z *= 0.25f; a.w *= 0.25f;
    *reinterpret_cast<float4*>(out + (size_t)r * KD + tid * 4) = a;
}

// ===========================================================================
// Fallback (round-1 proven fp32 path) — used only if ws_size is too small.
// ===========================================================================
#define FNS    32
#define FSLICE (NTGT / FNS)
#define FBM 128
#define FBN 128
#define FBK 16
#define FNTILE (FSLICE / FBN)
#define FLDA 132
#define FLDSS 33

__global__ void tinv_kernel(const float* __restrict__ T, float* __restrict__ tinv) {
    const int wave = threadIdx.x >> 6;
    const int lane = threadIdx.x & 63;
    const int row  = blockIdx.x * 4 + wave;
    const float* p = T + (size_t)row * KD;
    float s = 0.f;
#pragma unroll
    for (int j = 0; j < 4; ++j) {
        float4 v = *reinterpret_cast<const float4*>(p + lane * 4 + j * 256);
        s += v.x * v.x + v.y * v.y + v.z * v.z + v.w * v.w;
    }
#pragma unroll
    for (int off = 32; off; off >>= 1) s += __shfl_xor(s, off);
    if (lane == 0) tinv[row] = 1.0f / sqrtf(fmaxf(s, 1e-24f));
}

__global__ __launch_bounds__(256, 2)
void simtopk_kernel(const float* __restrict__ S, const float* __restrict__ T,
                    const float* __restrict__ tinv,
                    float* __restrict__ pval, int* __restrict__ pidx) {
    __shared__ float smem[2 * FBK * FLDA];
    __shared__ float tinvS[FBN];
    float* As = smem;
    float* Bs = smem + FBK * FLDA;
    float* Ss = smem;

    const int tid = threadIdx.x;
    const int tx = tid & 15, ty = tid >> 4;
    const int rb   = blockIdx.x;
    const int tgt0 = blockIdx.y * FSLICE;
    const size_t abase = (size_t)(rb * FBM) * KD;

    float t0 = -INFINITY, t1 = -INFINITY, t2 = -INFINITY, t3 = -INFINITY;
    int   i0 = 0, i1 = 0, i2 = 0, i3 = 0;

    for (int nt = 0; nt < FNTILE; ++nt) {
        const int tb = tgt0 + nt * FBN;
        float acc[8][8];
#pragma unroll
        for (int i = 0; i < 8; ++i)
#pragma unroll
            for (int j = 0; j < 8; ++j) acc[i][j] = 0.f;

        for (int kk = 0; kk < KD; kk += FBK) {
            const int rr = tid >> 2;
            const int c4 = (tid & 3) * 4;
#pragma unroll
            for (int h = 0; h < 2; ++h) {
                const int row = rr + h * 64;
                float4 av = *reinterpret_cast<const float4*>(S + abase + (size_t)row * KD + kk + c4);
                float4 bv = *reinterpret_cast<const float4*>(T + (size_t)(tb + row) * KD + kk + c4);
                As[(c4 + 0) * FLDA + row] = av.x; As[(c4 + 1) * FLDA + row] = av.y;
                As[(c4 + 2) * FLDA + row] = av.z; As[(c4 + 3) * FLDA + row] = av.w;
                Bs[(c4 + 0) * FLDA + row] = bv.x; Bs[(c4 + 1) * FLDA + row] = bv.y;
                Bs[(c4 + 2) * FLDA + row] = bv.z; Bs[(c4 + 3) * FLDA + row] = bv.w;
            }
            __syncthreads();
#pragma unroll
            for (int k = 0; k < FBK; ++k) {
                float a[8], b[8];
                *reinterpret_cast<float4*>(&a[0]) = *reinterpret_cast<float4*>(&As[k * FLDA + ty * 8]);
                *reinterpret_cast<float4*>(&a[4]) = *reinterpret_cast<float4*>(&As[k * FLDA + ty * 8 + 4]);
                *reinterpret_cast<float4*>(&b[0]) = *reinterpret_cast<float4*>(&Bs[k * FLDA + tx * 4]);
                *reinterpret_cast<float4*>(&b[4]) = *reinterpret_cast<float4*>(&Bs[k * FLDA + 64 + tx * 4]);
#pragma unroll
                for (int i = 0; i < 8; ++i)
#pragma unroll
                    for (int j = 0; j < 8; ++j)
                        acc[i][j] = fmaf(a[i], b[j], acc[i][j]);
            }
            __syncthreads();
        }

        if (tid < FBN) tinvS[tid] = tinv[tb + tid];
        __syncthreads();

#pragma unroll
        for (int cc = 0; cc < 4; ++cc) {
            const int g = cc >> 1;
            if ((tx >> 3) == (cc & 1)) {
                const int txl = tx & 7;
#pragma unroll
                for (int i = 0; i < 8; ++i) {
                    const int rrow = ty * 8 + i;
#pragma unroll
                    for (int j = 0; j < 4; ++j) {
                        const int colc = 4 * txl + j;
                        Ss[rrow * FLDSS + colc] = acc[i][g * 4 + j] * tinvS[cc * 32 + colc];
                    }
                }
            }
            __syncthreads();
            if (tid < FBM) {
#pragma unroll 4
                for (int c = 0; c < 32; ++c) {
                    const float v = Ss[tid * FLDSS + c];
                    if (v > t3) {
                        const int gi = tb + cc * 32 + c;
                        if (v > t0)      { t3=t2;i3=i2; t2=t1;i2=i1; t1=t0;i1=i0; t0=v;i0=gi; }
                        else if (v > t1) { t3=t2;i3=i2; t2=t1;i2=i1; t1=v;i1=gi; }
                        else if (v > t2) { t3=t2;i3=i2; t2=v;i2=gi; }
                        else             { t3=v;i3=gi; }
                    }
                }
            }
            __syncthreads();
        }
    }

    if (tid < FBM) {
        const int row = rb * FBM + tid;
        const size_t base = ((size_t)blockIdx.y * M + row) * 4;
        pval[base + 0] = t0; pval[base + 1] = t1; pval[base + 2] = t2; pval[base + 3] = t3;
        pidx[base + 0] = i0; pidx[base + 1] = i1; pidx[base + 2] = i2; pidx[base + 3] = i3;
    }
}

__global__ void merge_kernel(const float* __restrict__ pval, const int* __restrict__ pidx,
                             const float* __restrict__ T, float* __restrict__ out) {
    __shared__ float cv[FNS * 4];
    __shared__ int   ci[FNS * 4];
    __shared__ int   sel[4];
    const int r = blockIdx.x;
    const int tid = threadIdx.x;

    if (tid < FNS * 4) {
        const int s = tid >> 2, q = tid & 3;
        const size_t base = ((size_t)s * M + r) * 4 + q;
        cv[tid] = pval[base];
        ci[tid] = pidx[base];
    }
    __syncthreads();

    if (tid == 0) {
        float t0 = -INFINITY, t1 = -INFINITY, t2 = -INFINITY, t3 = -INFINITY;
        int   j0 = 0, j1 = 0, j2 = 0, j3 = 0;
        for (int c = 0; c < FNS * 4; ++c) {
            const float v = cv[c];
            if (v > t3) {
                const int gi = ci[c];
                if (v > t0)      { t3=t2;j3=j2; t2=t1;j2=j1; t1=t0;j1=j0; t0=v;j0=gi; }
                else if (v > t1) { t3=t2;j3=j2; t2=t1;j2=j1; t1=v;j1=gi; }
                else if (v > t2) { t3=t2;j3=j2; t2=v;j2=gi; }
                else             { t3=v;j3=gi; }
            }
        }
        sel[0] = j0; sel[1] = j1; sel[2] = j2; sel[3] = j3;
    }
    __syncthreads();

    const int d = tid * 4;
    float4 a = make_float4(0.f, 0.f, 0.f, 0.f);
#pragma unroll
    for (int q = 0; q < 4; ++q) {
        const float4 v = *reinterpret_cast<const float4*>(T + (size_t)sel[q] * KD + d);
        a.x += v.x; a.y += v.y; a.z += v.z; a.w += v.w;
    }
    a.x *= 0.25f; a.y *= 0.25f; a.z *= 0.25f; a.w *= 0.25f;
    *reinterpret_cast<float4*>(out + (size_t)r * KD + d) = a;
}

// ---------------------------------------------------------------------------
extern "C" void kernel_launch(void* const* d_in, const int* in_sizes, int n_in,
                              void* d_out, int out_size, void* d_ws, size_t ws_size,
                              hipStream_t stream) {
    const float* S = (const float*)d_in[0];   // [4096,1024]
    const float* T = (const float*)d_in[1];   // [65536,1024]
    float* out = (float*)d_out;               // [4096,1024]

    const size_t sz_tinv = (size_t)NTGT * 4;                 // 256 KB
    const size_t sz_Sb   = (size_t)M * KD * 2;               // 8 MB
    const size_t sz_Tb   = (size_t)NTGT * KD * 2;            // 128 MB
    const size_t sz_cand = (size_t)M * 256 * 4;              // 4 MB
    const size_t need = sz_tinv + sz_Sb + sz_Tb + sz_cand;   // ~140.3 MB

    if (ws_size >= need) {
        float*    tinv = (float*)d_ws;
        ushort*   Sb   = (ushort*)((char*)d_ws + sz_tinv);
        ushort*   Tb   = (ushort*)((char*)d_ws + sz_tinv + sz_Sb);
        uint32_t* cand = (uint32_t*)((char*)d_ws + sz_tinv + sz_Sb + sz_Tb);

        prep_targets<<<NTGT / 4, 256, 0, stream>>>(T, tinv, Tb);
        prep_source<<<M / 4, 256, 0, stream>>>(S, Sb);
        screen_kernel<<<dim3(M / BS, NS), 256, 0, stream>>>(Sb, Tb, cand);
        final_kernel<<<M, 256, 0, stream>>>(cand, S, T, tinv, out);
    } else {
        // round-1 fp32 fallback (~7 ms, proven correct)
        float* tinv = (float*)d_ws;
        float* pval = tinv + NTGT;
        int*   pidx = (int*)(pval + (size_t)FNS * M * 4);

        tinv_kernel<<<NTGT / 4, 256, 0, stream>>>(T, tinv);
        simtopk_kernel<<<dim3(M / FBM, FNS), 256, 0, stream>>>(S, T, tinv, pval, pidx);
        merge_kernel<<<M, 256, 0, stream>>>(pval, pidx, T, out);
    }
}